// Round 10
// baseline (318.047 us; speedup 1.0000x reference)
//
#include <hip/hip_runtime.h>
#include <hip/hip_bf16.h>
#include <math.h>

// LiquidNeuralNetwork: B=4096, IN=512, HS={256,128,64}, S=64, OUT=12
// Round 10: transposed MFMA (A=Wt, B=X) so s lives in the register dim:
// Wo-dot happens in-register, shuffle tree shrinks 40 -> 4 shfl/thread.
// LUT activation + XOR swizzle retained from r9.

#define BATCH 4096

typedef __bf16 bf16x8 __attribute__((ext_vector_type(8)));
typedef float floatx4 __attribute__((ext_vector_type(4)));

__device__ __forceinline__ void gl_lds16(const void* g, void* l) {
    __builtin_amdgcn_global_load_lds(
        (const __attribute__((address_space(1))) void*)g,
        (__attribute__((address_space(3))) void*)l, 16, 0, 0);
}

// ---------- merged conversion pre-pass + table build ----------

__device__ __forceinline__ void wconv_tile(const float* __restrict__ Wi,
                                           __hip_bfloat16* __restrict__ Wt,
                                           int K, int n, int k0, int t)
{
    __shared__ float lds[64][65];
    const float* src = Wi + ((size_t)n * K + k0) * 64;
#pragma unroll
    for (int i = 0; i < 4; ++i) {
        int idx = t + i * 256;
        int r = idx >> 4;
        int s4 = (idx & 15) * 4;
        float4 v = *(const float4*)(src + (size_t)r * 64 + s4);
        lds[s4 + 0][r] = v.x;
        lds[s4 + 1][r] = v.y;
        lds[s4 + 2][r] = v.z;
        lds[s4 + 3][r] = v.w;
    }
    __syncthreads();
    __hip_bfloat16* dst = Wt + (size_t)n * 64 * K + k0;
#pragma unroll
    for (int i = 0; i < 4; ++i) {
        int idx = t + i * 256;
        int s = idx >> 4;
        int k4 = (idx & 15) * 4;
        union { ushort4 u4; __hip_bfloat16 b[4]; } o;
        o.b[0] = __float2bfloat16(lds[s][k4 + 0]);
        o.b[1] = __float2bfloat16(lds[s][k4 + 1]);
        o.b[2] = __float2bfloat16(lds[s][k4 + 2]);
        o.b[3] = __float2bfloat16(lds[s][k4 + 3]);
        *(ushort4*)(dst + (size_t)s * K + k4) = o.u4;
    }
}

// [0,2048): xconv; [2048,4096): Wi0; [4096,4608): Wi1; [4608,4736): Wi2;
// 4736: activation table build (1040 floats, entries >=1025 duplicate f(8)).
__global__ __launch_bounds__(256) void conv_all(
    const float* __restrict__ x, __hip_bfloat16* __restrict__ xb,
    const float* __restrict__ Wi0, const float* __restrict__ Wi1,
    const float* __restrict__ Wi2,
    __hip_bfloat16* __restrict__ Wt0, __hip_bfloat16* __restrict__ Wt1,
    __hip_bfloat16* __restrict__ Wt2, float* __restrict__ Tg)
{
    int bid = blockIdx.x;
    int t = threadIdx.x;
    if (bid < 2048) {
        int g = bid * 256 + t;
        float4 v = ((const float4*)x)[g];
        union { ushort4 u4; __hip_bfloat16 b[4]; } o;
        o.b[0] = __float2bfloat16(v.x);
        o.b[1] = __float2bfloat16(v.y);
        o.b[2] = __float2bfloat16(v.z);
        o.b[3] = __float2bfloat16(v.w);
        ((ushort4*)xb)[g] = o.u4;
    } else if (bid < 4096) {
        int r = bid - 2048;
        wconv_tile(Wi0, Wt0, 512, r >> 3, (r & 7) * 64, t);
    } else if (bid < 4608) {
        int r = bid - 4096;
        wconv_tile(Wi1, Wt1, 256, r >> 2, (r & 3) * 64, t);
    } else if (bid < 4736) {
        int r = bid - 4608;
        wconv_tile(Wi2, Wt2, 128, r >> 1, (r & 1) * 64, t);
    } else {
#pragma unroll
        for (int i = 0; i < 5; ++i) {
            int e = t + 256 * i;
            if (e < 1040) {
                int ec = e < 1024 ? e : 1024;
                float ve = (float)(ec - 512) * 0.015625f;   // [-8, 8]
                Tg[e] = tanhf(ve) + 0.1f * sinf(0.5f * ve) * cosf(0.3f * ve);
            }
        }
    }
}

// ---------- MFMA proj: t[b,n] = sum_s act(x@Wi + bi + bl)*Wo + bo ----------
// Block: 256 threads = 4 waves (2 batch-halves x 2 neurons); 64 batch x 2 n.
// TRANSPOSED: A = Wt s-rows, B = X batch-rows -> D[s = rt*16+qd*4+reg,
// b = ct*16+m]. Wo-dot is in-register; reduce over qd only (shfl 16,32).

__global__ __launch_bounds__(256, 4) void liquid_proj_mfma(
    const __hip_bfloat16* __restrict__ X,   // [B][K] bf16
    const __hip_bfloat16* __restrict__ Wt,  // [Nn][64][K] bf16
    const float* __restrict__ bi, const float* __restrict__ bl,
    const float* __restrict__ Wo, const float* __restrict__ bo,
    const float* __restrict__ Tg,           // [1040] activation table
    __hip_bfloat16* __restrict__ t, int K, int Nn)
{
    __shared__ __align__(16) __hip_bfloat16 As[64 * 64];    // 8 KB  (X tile)
    __shared__ __align__(16) __hip_bfloat16 Bs[128 * 64];   // 16 KB (Wt tile)
    __shared__ __align__(16) float Tt[1040];                // 4.16 KB

    const int tid = threadIdx.x;
    const int wid = tid >> 6;
    const int wb = wid & 1;               // batch half (32 rows)
    const int wn = wid >> 1;              // neuron within block [0,2)
    const int lane = tid & 63;
    const int m = lane & 15;
    const int qd = lane >> 4;

    // swizzle: bid = (n_grp*8 + row_local)*8 + xcd ; row_grp = row_local*8+xcd
    const int bid = blockIdx.x;
    const int xcd = bid & 7;
    const int sw = bid >> 3;
    const int n_grp = sw >> 3;
    const int row_grp = ((sw & 7) << 3) | xcd;
    const int row0 = row_grp * 64;
    const int n0 = n_grp * 2;
    const int n = n0 + wn;

    // table -> LDS: 260 16B chunks
    gl_lds16(Tg + tid * 4, (void*)(Tt + tid * 4));
    if (tid < 4)
        gl_lds16(Tg + 1024 + tid * 4, (void*)(Tt + 1024 + tid * 4));

    // bias folded into acc init; s = rt*16 + qd*4 + reg -> float4 loads
    floatx4 acc[4][2];
#pragma unroll
    for (int rt = 0; rt < 4; ++rt) {
        int sb = n * 64 + rt * 16 + qd * 4;
        float4 b4i = *(const float4*)(bi + sb);
        float4 b4l = *(const float4*)(bl + sb);
        floatx4 b4 = {b4i.x + b4l.x, b4i.y + b4l.y, b4i.z + b4l.z, b4i.w + b4l.w};
        acc[rt][0] = b4;
        acc[rt][1] = b4;
    }

    // A(X) staging: slots tid, tid+256; source chunk (r, q^(r&7))
    const int ar0 = tid >> 3;
    const int aq0 = (tid & 7) ^ (ar0 & 7);
    const int ar1 = (tid + 256) >> 3;
    const int aq1 = ((tid + 256) & 7) ^ (ar1 & 7);
    const __hip_bfloat16* Xr0 = X + (size_t)(row0 + ar0) * K + aq0 * 8;
    const __hip_bfloat16* Xr1 = X + (size_t)(row0 + ar1) * K + aq1 * 8;

    // B(Wt) staging: 1024 chunks, 4/thread; slot Li, source chunk (c, q^(c&7))
    const __hip_bfloat16* bsrc[4];
#pragma unroll
    for (int i = 0; i < 4; ++i) {
        int Li = i * 256 + tid;
        int c = Li >> 3;
        int q = (Li & 7) ^ (c & 7);
        bsrc[i] = Wt + ((size_t)(n0 + (c >> 6)) * 64 + (c & 63)) * K + q * 8;
    }

    for (int k0 = 0; k0 < K; k0 += 64) {
        gl_lds16(Xr0 + k0, (void*)(As + tid * 8));
        gl_lds16(Xr1 + k0, (void*)(As + (tid + 256) * 8));
#pragma unroll
        for (int i = 0; i < 4; ++i)
            gl_lds16(bsrc[i] + k0, (void*)(Bs + ((size_t)i * 256 + tid) * 8));
        __syncthreads();
#pragma unroll
        for (int kk = 0; kk < 2; ++kk) {
            bf16x8 af[4], bfr[2];
#pragma unroll
            for (int rt = 0; rt < 4; ++rt) {          // A = Wt s-rows
                int c2 = wn * 64 + rt * 16 + m;
                int slot = c2 * 8 + ((kk * 4 + qd) ^ (c2 & 7));
                af[rt] = *(const bf16x8*)(Bs + slot * 8);
            }
#pragma unroll
            for (int ct = 0; ct < 2; ++ct) {          // B = X batch-rows
                int r2 = wb * 32 + ct * 16 + m;
                int slot = r2 * 8 + ((kk * 4 + qd) ^ (r2 & 7));
                bfr[ct] = *(const bf16x8*)(As + slot * 8);
            }
#pragma unroll
            for (int rt = 0; rt < 4; ++rt)
#pragma unroll
                for (int ct = 0; ct < 2; ++ct)
                    acc[rt][ct] = __builtin_amdgcn_mfma_f32_16x16x32_bf16(
                        af[rt], bfr[ct], acc[rt][ct], 0, 0, 0);
        }
        __syncthreads();
    }

    // Epilogue: s = rt*16+qd*4+reg, b = wb*32+ct*16+m. In-register Wo-dot.
    float wo[4][4];
#pragma unroll
    for (int rt = 0; rt < 4; ++rt) {
        float4 w4 = *(const float4*)(Wo + n * 64 + rt * 16 + qd * 4);
        wo[rt][0] = w4.x; wo[rt][1] = w4.y; wo[rt][2] = w4.z; wo[rt][3] = w4.w;
    }
    float bov = bo[n];
    float p[2] = {0.f, 0.f};
#pragma unroll
    for (int ct = 0; ct < 2; ++ct)
#pragma unroll
        for (int rt = 0; rt < 4; ++rt)
#pragma unroll
            for (int reg = 0; reg < 4; ++reg) {
                float v = acc[rt][ct][reg];
                float u = fmaf(v, 64.f, 512.f);
                u = fminf(fmaxf(u, 0.f), 1038.f);
                float fi = floorf(u);
                int ii = (int)fi;
                float fr = u - fi;
                float t0 = Tt[ii];
                float t1 = Tt[ii + 1];
                p[ct] = fmaf(fmaf(fr, t1 - t0, t0), wo[rt][reg], p[ct]);
            }
#pragma unroll
    for (int ct = 0; ct < 2; ++ct) {
        p[ct] += __shfl_xor(p[ct], 16, 64);
        p[ct] += __shfl_xor(p[ct], 32, 64);
    }
    if (qd == 0) {
#pragma unroll
        for (int ct = 0; ct < 2; ++ct)
            t[(size_t)(row0 + wb * 32 + ct * 16 + m) * Nn + n] =
                __float2bfloat16(p[ct] + bov);
    }
}

// ---------- lateral (+ fused output head on final layer) ----------

template <int NN, int NNSH, bool FINAL>
__global__ __launch_bounds__(256) void lateral_fused(
    const __hip_bfloat16* __restrict__ t,   // [B][NN] bf16
    const float* __restrict__ Lm,           // [NN][NN]
    const float* __restrict__ a,            // [NN]
    __hip_bfloat16* __restrict__ h,         // [B][NN] bf16 (unused if FINAL)
    const float* __restrict__ Wout,         // [64][12] (FINAL only)
    const float* __restrict__ bout,         // [12]
    float* __restrict__ y)                  // [B][12]
{
    constexpr int RPT = NN / 16;
    __shared__ float tbT[NN][20];
    __shared__ float hb[16][65];

    const int tid = threadIdx.x;
    const int row0 = blockIdx.x * 16;

#pragma unroll
    for (int i = 0; i < NN / 16; ++i) {
        int idx = tid + i * 256;
        int r = idx >> NNSH;
        int c = idx & (NN - 1);
        tbT[c][r] = __bfloat162float(t[(size_t)(row0 + r) * NN + c]);
    }
    __syncthreads();

    const int c = tid & (NN - 1);
    const int rb = (tid >> NNSH) * RPT;
    float acc[RPT];
#pragma unroll
    for (int r = 0; r < RPT; ++r) acc[r] = 0.f;

    for (int mm = 0; mm < NN; ++mm) {
        float lv = Lm[mm * NN + c];
#pragma unroll
        for (int rr = 0; rr < RPT / 4; ++rr) {
            float4 tv = *(const float4*)&tbT[mm][rb + 4 * rr];
            acc[4 * rr + 0] += tv.x * lv;
            acc[4 * rr + 1] += tv.y * lv;
            acc[4 * rr + 2] += tv.z * lv;
            acc[4 * rr + 3] += tv.w * lv;
        }
    }
    float av = a[c];
#pragma unroll
    for (int r = 0; r < RPT; ++r) {
        float hv = (tbT[c][rb + r] + 0.1f * acc[r]) * av;
        if constexpr (FINAL) {
            hb[rb + r][c] = hv;
        } else {
            h[(size_t)(row0 + rb + r) * NN + c] = __float2bfloat16(hv);
        }
    }
    if constexpr (FINAL) {
        __syncthreads();
        if (tid < 192) {
            int r = tid / 12, o = tid - 12 * r;
            float accy = bout[o];
#pragma unroll
            for (int k = 0; k < 64; ++k)
                accy += hb[r][k] * Wout[k * 12 + o];
            y[(size_t)(row0 + r) * 12 + o] = accy;
        }
    }
}

// ---------- fp32 fallback path (round-2 verified) ----------

__global__ __launch_bounds__(256) void liquid_proj_f32(
    const float* __restrict__ x, const float* __restrict__ Wi,
    const float* __restrict__ bi, const float* __restrict__ bl,
    const float* __restrict__ Wo, const float* __restrict__ bo,
    float* __restrict__ t, int K, int Nn)
{
    __shared__ float xs[16][65];
    __shared__ float ws[16][65];
    const int tid = threadIdx.x;
    const int tx = tid & 15, ty = tid >> 4;
    const int row0 = blockIdx.x * 64;
    const int n = blockIdx.y;
    const float* Wn = Wi + (size_t)n * K * 64;
    float acc[4][4] = {};
    for (int k0 = 0; k0 < K; k0 += 16) {
#pragma unroll
        for (int i = 0; i < 4; ++i) {
            int li = tid + 256 * i;
            xs[li & 15][li >> 4] = x[(size_t)(row0 + (li >> 4)) * K + k0 + (li & 15)];
        }
#pragma unroll
        for (int i = 0; i < 4; ++i) {
            int li = tid + 256 * i;
            ws[li >> 6][li & 63] = Wn[(size_t)(k0 + (li >> 6)) * 64 + (li & 63)];
        }
        __syncthreads();
#pragma unroll
        for (int kk = 0; kk < 16; ++kk) {
            float xa[4], wb[4];
#pragma unroll
            for (int i = 0; i < 4; ++i) xa[i] = xs[kk][4 * ty + i];
#pragma unroll
            for (int j = 0; j < 4; ++j) wb[j] = ws[kk][4 * tx + j];
#pragma unroll
            for (int i = 0; i < 4; ++i)
#pragma unroll
                for (int j = 0; j < 4; ++j) acc[i][j] += xa[i] * wb[j];
        }
        __syncthreads();
    }
    float part[4] = {0.f, 0.f, 0.f, 0.f};
#pragma unroll
    for (int j = 0; j < 4; ++j) {
        int cc = 4 * tx + j;
        float bias = bi[n * 64 + cc] + bl[n * 64 + cc];
        float wov = Wo[n * 64 + cc];
#pragma unroll
        for (int i = 0; i < 4; ++i) {
            float v = acc[i][j] + bias;
            part[i] += (tanhf(v) + 0.1f * sinf(0.5f * v) * cosf(0.3f * v)) * wov;
        }
    }
#pragma unroll
    for (int mk = 1; mk < 16; mk <<= 1)
#pragma unroll
        for (int i = 0; i < 4; ++i) part[i] += __shfl_xor(part[i], mk, 64);
    if (tx == 0) {
        float b = bo[n];
#pragma unroll
        for (int i = 0; i < 4; ++i)
            t[(size_t)(row0 + 4 * ty + i) * Nn + n] = part[i] + b;
    }
}

__global__ void lateral_f32_kernel(const float* __restrict__ t,
                                   const float* __restrict__ L,
                                   const float* __restrict__ a,
                                   float* __restrict__ h, int Nn)
{
    extern __shared__ float tb[];
    const int b = blockIdx.x;
    const int n = threadIdx.x;
    tb[n] = t[(size_t)b * Nn + n];
    __syncthreads();
    float acc = 0.f;
    for (int mm = 0; mm < Nn; ++mm)
        acc += tb[mm] * L[(size_t)mm * Nn + n];
    h[(size_t)b * Nn + n] = (tb[n] + 0.1f * acc) * a[n];
}

__global__ void out_f32_kernel(const float* __restrict__ h,
                               const float* __restrict__ Wout,
                               const float* __restrict__ bout,
                               float* __restrict__ y)
{
    int g = blockIdx.x * blockDim.x + threadIdx.x;
    if (g >= BATCH * 12) return;
    int b = g / 12, o = g - 12 * b;
    float acc = bout[o];
    const float* hb = h + (size_t)b * 64;
#pragma unroll
    for (int k = 0; k < 64; ++k) acc += hb[k] * Wout[k * 12 + o];
    y[g] = acc;
}

extern "C" void kernel_launch(void* const* d_in, const int* in_sizes, int n_in,
                              void* d_out, int out_size, void* d_ws, size_t ws_size,
                              hipStream_t stream)
{
    (void)in_sizes; (void)n_in; (void)out_size;
    const float* x = (const float*)d_in[0];
    const float* Wout = (const float*)d_in[22];
    const float* bout = (const float*)d_in[23];
    const int dims[4] = {512, 256, 128, 64};
    char* ws = (char*)d_ws;
    const size_t MB = 1024u * 1024u;

    if (ws_size >= 28 * MB) {
        // Wt0 [0,16) Wt1 [16,20) Wt2 [20,21) xb [21,25) (h0 [21,23), h1 [23,24))
        // tbuf [25,27)  table [27, 27+4.2KB)
        __hip_bfloat16* Wt0 = (__hip_bfloat16*)ws;
        __hip_bfloat16* Wt1 = (__hip_bfloat16*)(ws + 16 * MB);
        __hip_bfloat16* Wt2 = (__hip_bfloat16*)(ws + 20 * MB);
        __hip_bfloat16* Wts[3] = {Wt0, Wt1, Wt2};
        __hip_bfloat16* xb = (__hip_bfloat16*)(ws + 21 * MB);
        __hip_bfloat16* h0 = xb;
        __hip_bfloat16* h1 = (__hip_bfloat16*)(ws + 23 * MB);
        __hip_bfloat16* tbuf = (__hip_bfloat16*)(ws + 25 * MB);
        float* Tg = (float*)(ws + 27 * MB);

        conv_all<<<4737, 256, 0, stream>>>(
            x, xb, (const float*)d_in[1], (const float*)d_in[8],
            (const float*)d_in[15], Wt0, Wt1, Wt2, Tg);

        const __hip_bfloat16* prev = xb;
        const __hip_bfloat16* hbuf[3] = {h0, h1, nullptr};
        for (int l = 0; l < 3; ++l) {
            const float* bi = (const float*)d_in[1 + 7 * l + 1];
            const float* bl = (const float*)d_in[1 + 7 * l + 2];
            const float* Wo = (const float*)d_in[1 + 7 * l + 3];
            const float* bo = (const float*)d_in[1 + 7 * l + 4];
            const float* L  = (const float*)d_in[1 + 7 * l + 5];
            const float* a  = (const float*)d_in[1 + 7 * l + 6];
            const int K = dims[l], Nn = dims[l + 1];

            liquid_proj_mfma<<<64 * (Nn / 2), 256, 0, stream>>>(
                prev, Wts[l], bi, bl, Wo, bo, Tg, tbuf, K, Nn);
            if (l == 0)
                lateral_fused<256, 8, false><<<BATCH / 16, 256, 0, stream>>>(
                    tbuf, L, a, h0, nullptr, nullptr, nullptr);
            else if (l == 1)
                lateral_fused<128, 7, false><<<BATCH / 16, 256, 0, stream>>>(
                    tbuf, L, a, h1, nullptr, nullptr, nullptr);
            else
                lateral_fused<64, 6, true><<<BATCH / 16, 256, 0, stream>>>(
                    tbuf, L, a, nullptr, Wout, bout, (float*)d_out);
            prev = hbuf[l];
        }
    } else {
        float* tbufs[3] = {(float*)ws, (float*)ws, (float*)(ws + 4 * MB)};
        float* hs[3] = {(float*)(ws + 4 * MB), (float*)(ws + 2 * MB),
                        (float*)(ws + 5 * MB)};
        const float* prev = x;
        for (int l = 0; l < 3; ++l) {
            const float* Wi = (const float*)d_in[1 + 7 * l + 0];
            const float* bi = (const float*)d_in[1 + 7 * l + 1];
            const float* bl = (const float*)d_in[1 + 7 * l + 2];
            const float* Wo = (const float*)d_in[1 + 7 * l + 3];
            const float* bo = (const float*)d_in[1 + 7 * l + 4];
            const float* L  = (const float*)d_in[1 + 7 * l + 5];
            const float* a  = (const float*)d_in[1 + 7 * l + 6];
            const int K = dims[l], Nn = dims[l + 1];
            liquid_proj_f32<<<dim3(BATCH / 64, Nn), 256, 0, stream>>>(
                prev, Wi, bi, bl, Wo, bo, tbufs[l], K, Nn);
            lateral_f32_kernel<<<BATCH, Nn, Nn * sizeof(float), stream>>>(
                tbufs[l], L, a, hs[l], Nn);
            prev = hs[l];
        }
        out_f32_kernel<<<(BATCH * 12 + 255) / 256, 256, 0, stream>>>(
            hs[2], Wout, bout, (float*)d_out);
    }
}

// Round 11
// 285.387 us; speedup vs baseline: 1.1144x; 1.1144x over previous
//
#include <hip/hip_runtime.h>
#include <hip/hip_bf16.h>
#include <math.h>

// LiquidNeuralNetwork: B=4096, IN=512, HS={256,128,64}, S=64, OUT=12
// Round 11: LDS-BW attack. Per-wave tile 64s x 64b (bytes/FLOP 0.047->0.031),
// 512-thread blocks = 128 batch x 4 neurons (halves X staging duplication).
// Transposed MFMA + LUT activation + XOR swizzle retained.

#define BATCH 4096

typedef __bf16 bf16x8 __attribute__((ext_vector_type(8)));
typedef float floatx4 __attribute__((ext_vector_type(4)));

__device__ __forceinline__ void gl_lds16(const void* g, void* l) {
    __builtin_amdgcn_global_load_lds(
        (const __attribute__((address_space(1))) void*)g,
        (__attribute__((address_space(3))) void*)l, 16, 0, 0);
}

// ---------- merged conversion pre-pass + table build ----------

__device__ __forceinline__ void wconv_tile(const float* __restrict__ Wi,
                                           __hip_bfloat16* __restrict__ Wt,
                                           int K, int n, int k0, int t)
{
    __shared__ float lds[64][65];
    const float* src = Wi + ((size_t)n * K + k0) * 64;
#pragma unroll
    for (int i = 0; i < 4; ++i) {
        int idx = t + i * 256;
        int r = idx >> 4;
        int s4 = (idx & 15) * 4;
        float4 v = *(const float4*)(src + (size_t)r * 64 + s4);
        lds[s4 + 0][r] = v.x;
        lds[s4 + 1][r] = v.y;
        lds[s4 + 2][r] = v.z;
        lds[s4 + 3][r] = v.w;
    }
    __syncthreads();
    __hip_bfloat16* dst = Wt + (size_t)n * 64 * K + k0;
#pragma unroll
    for (int i = 0; i < 4; ++i) {
        int idx = t + i * 256;
        int s = idx >> 4;
        int k4 = (idx & 15) * 4;
        union { ushort4 u4; __hip_bfloat16 b[4]; } o;
        o.b[0] = __float2bfloat16(lds[s][k4 + 0]);
        o.b[1] = __float2bfloat16(lds[s][k4 + 1]);
        o.b[2] = __float2bfloat16(lds[s][k4 + 2]);
        o.b[3] = __float2bfloat16(lds[s][k4 + 3]);
        *(ushort4*)(dst + (size_t)s * K + k4) = o.u4;
    }
}

// [0,2048): xconv; [2048,4096): Wi0; [4096,4608): Wi1; [4608,4736): Wi2;
// 4736: activation table build (1040 floats, entries >=1025 duplicate f(8)).
__global__ __launch_bounds__(256) void conv_all(
    const float* __restrict__ x, __hip_bfloat16* __restrict__ xb,
    const float* __restrict__ Wi0, const float* __restrict__ Wi1,
    const float* __restrict__ Wi2,
    __hip_bfloat16* __restrict__ Wt0, __hip_bfloat16* __restrict__ Wt1,
    __hip_bfloat16* __restrict__ Wt2, float* __restrict__ Tg)
{
    int bid = blockIdx.x;
    int t = threadIdx.x;
    if (bid < 2048) {
        int g = bid * 256 + t;
        float4 v = ((const float4*)x)[g];
        union { ushort4 u4; __hip_bfloat16 b[4]; } o;
        o.b[0] = __float2bfloat16(v.x);
        o.b[1] = __float2bfloat16(v.y);
        o.b[2] = __float2bfloat16(v.z);
        o.b[3] = __float2bfloat16(v.w);
        ((ushort4*)xb)[g] = o.u4;
    } else if (bid < 4096) {
        int r = bid - 2048;
        wconv_tile(Wi0, Wt0, 512, r >> 3, (r & 7) * 64, t);
    } else if (bid < 4608) {
        int r = bid - 4096;
        wconv_tile(Wi1, Wt1, 256, r >> 2, (r & 3) * 64, t);
    } else if (bid < 4736) {
        int r = bid - 4608;
        wconv_tile(Wi2, Wt2, 128, r >> 1, (r & 1) * 64, t);
    } else {
#pragma unroll
        for (int i = 0; i < 5; ++i) {
            int e = t + 256 * i;
            if (e < 1040) {
                int ec = e < 1024 ? e : 1024;
                float ve = (float)(ec - 512) * 0.015625f;   // [-8, 8]
                Tg[e] = tanhf(ve) + 0.1f * sinf(0.5f * ve) * cosf(0.3f * ve);
            }
        }
    }
}

// ---------- MFMA proj: t[b,n] = sum_s act(x@Wi + bi + bl)*Wo + bo ----------
// Block: 512 threads = 8 waves (2 batch-halves x 4 neurons); 128 batch x 4 n.
// Per-wave tile 64s x 64b: acc[4][4]. TRANSPOSED (A=Wt, B=X):
// D[s = rt*16+qd*4+reg][b = wb*64+ct*16+m]. In-register Wo-dot, 2-shfl reduce.

__global__ __launch_bounds__(512, 4) void liquid_proj_mfma(
    const __hip_bfloat16* __restrict__ X,   // [B][K] bf16
    const __hip_bfloat16* __restrict__ Wt,  // [Nn][64][K] bf16
    const float* __restrict__ bi, const float* __restrict__ bl,
    const float* __restrict__ Wo, const float* __restrict__ bo,
    const float* __restrict__ Tg,           // [1040] activation table
    __hip_bfloat16* __restrict__ t, int K, int Nn)
{
    __shared__ __align__(16) __hip_bfloat16 As[128 * 64];   // 16 KB (X tile)
    __shared__ __align__(16) __hip_bfloat16 Bs[256 * 64];   // 32 KB (Wt tile)
    __shared__ __align__(16) float Tt[1040];                // 4.16 KB

    const int tid = threadIdx.x;
    const int wid = tid >> 6;
    const int wb = wid & 1;               // batch half (64 rows each)
    const int wn = wid >> 1;              // neuron within block [0,4)
    const int lane = tid & 63;
    const int m = lane & 15;
    const int qd = lane >> 4;

    // swizzle: bid = (n_grp*4 + row_local)*8 + xcd ; row_grp = row_local*8+xcd
    const int bid = blockIdx.x;
    const int xcd = bid & 7;
    const int sw = bid >> 3;
    const int n_grp = sw >> 2;
    const int row_grp = ((sw & 3) << 3) | xcd;   // [0,32)
    const int row0 = row_grp * 128;
    const int n0 = n_grp * 4;
    const int n = n0 + wn;

    // table -> LDS: 260 16B chunks
    if (tid < 260)
        gl_lds16(Tg + tid * 4, (void*)(Tt + tid * 4));

    // bias folded into acc init; s = rt*16 + qd*4 + reg (same for all ct)
    floatx4 acc[4][4];
#pragma unroll
    for (int rt = 0; rt < 4; ++rt) {
        int sb = n * 64 + rt * 16 + qd * 4;
        float4 b4i = *(const float4*)(bi + sb);
        float4 b4l = *(const float4*)(bl + sb);
        floatx4 b4 = {b4i.x + b4l.x, b4i.y + b4l.y, b4i.z + b4l.z, b4i.w + b4l.w};
#pragma unroll
        for (int ct = 0; ct < 4; ++ct)
            acc[rt][ct] = b4;
    }

    // A(X) staging: 1024 chunks, 2/thread; slot c, source chunk (r, q^(r&7))
    const int ar0 = tid >> 3;
    const int aq0 = (tid & 7) ^ (ar0 & 7);
    const int ar1 = (tid + 512) >> 3;
    const int aq1 = ((tid + 512) & 7) ^ (ar1 & 7);
    const __hip_bfloat16* Xr0 = X + (size_t)(row0 + ar0) * K + aq0 * 8;
    const __hip_bfloat16* Xr1 = X + (size_t)(row0 + ar1) * K + aq1 * 8;

    // B(Wt) staging: 2048 chunks, 4/thread
    const __hip_bfloat16* bsrc[4];
#pragma unroll
    for (int i = 0; i < 4; ++i) {
        int Li = i * 512 + tid;
        int c = Li >> 3;                 // s-row [0,256)
        int q = (Li & 7) ^ (c & 7);
        bsrc[i] = Wt + ((size_t)(n0 + (c >> 6)) * 64 + (c & 63)) * K + q * 8;
    }

    for (int k0 = 0; k0 < K; k0 += 64) {
        gl_lds16(Xr0 + k0, (void*)(As + tid * 8));
        gl_lds16(Xr1 + k0, (void*)(As + ((size_t)tid + 512) * 8));
#pragma unroll
        for (int i = 0; i < 4; ++i)
            gl_lds16(bsrc[i] + k0, (void*)(Bs + ((size_t)i * 512 + tid) * 8));
        __syncthreads();
#pragma unroll
        for (int kk = 0; kk < 2; ++kk) {
            bf16x8 af[4], bfr[4];
#pragma unroll
            for (int rt = 0; rt < 4; ++rt) {          // A = Wt s-rows
                int sr = wn * 64 + rt * 16 + m;
                int slot = sr * 8 + ((kk * 4 + qd) ^ (sr & 7));
                af[rt] = *(const bf16x8*)(Bs + slot * 8);
            }
#pragma unroll
            for (int ct = 0; ct < 4; ++ct) {          // B = X batch-rows
                int br = wb * 64 + ct * 16 + m;
                int slot = br * 8 + ((kk * 4 + qd) ^ (br & 7));
                bfr[ct] = *(const bf16x8*)(As + slot * 8);
            }
#pragma unroll
            for (int rt = 0; rt < 4; ++rt)
#pragma unroll
                for (int ct = 0; ct < 4; ++ct)
                    acc[rt][ct] = __builtin_amdgcn_mfma_f32_16x16x32_bf16(
                        af[rt], bfr[ct], acc[rt][ct], 0, 0, 0);
        }
        __syncthreads();
    }

    // Epilogue: s = rt*16+qd*4+reg, b = wb*64+ct*16+m. In-register Wo-dot.
    float wo[4][4];
#pragma unroll
    for (int rt = 0; rt < 4; ++rt) {
        float4 w4 = *(const float4*)(Wo + n * 64 + rt * 16 + qd * 4);
        wo[rt][0] = w4.x; wo[rt][1] = w4.y; wo[rt][2] = w4.z; wo[rt][3] = w4.w;
    }
    float bov = bo[n];
    float p[4] = {0.f, 0.f, 0.f, 0.f};
#pragma unroll
    for (int ct = 0; ct < 4; ++ct)
#pragma unroll
        for (int rt = 0; rt < 4; ++rt)
#pragma unroll
            for (int reg = 0; reg < 4; ++reg) {
                float v = acc[rt][ct][reg];
                float u = fmaf(v, 64.f, 512.f);
                u = fminf(fmaxf(u, 0.f), 1038.f);
                float fi = floorf(u);
                int ii = (int)fi;
                float fr = u - fi;
                float t0 = Tt[ii];
                float t1 = Tt[ii + 1];
                p[ct] = fmaf(fmaf(fr, t1 - t0, t0), wo[rt][reg], p[ct]);
            }
#pragma unroll
    for (int ct = 0; ct < 4; ++ct) {
        p[ct] += __shfl_xor(p[ct], 16, 64);
        p[ct] += __shfl_xor(p[ct], 32, 64);
    }
    if (qd == 0) {
#pragma unroll
        for (int ct = 0; ct < 4; ++ct)
            t[(size_t)(row0 + wb * 64 + ct * 16 + m) * Nn + n] =
                __float2bfloat16(p[ct] + bov);
    }
}

// ---------- lateral (+ fused output head on final layer) ----------

template <int NN, int NNSH, bool FINAL>
__global__ __launch_bounds__(256) void lateral_fused(
    const __hip_bfloat16* __restrict__ t,   // [B][NN] bf16
    const float* __restrict__ Lm,           // [NN][NN]
    const float* __restrict__ a,            // [NN]
    __hip_bfloat16* __restrict__ h,         // [B][NN] bf16 (unused if FINAL)
    const float* __restrict__ Wout,         // [64][12] (FINAL only)
    const float* __restrict__ bout,         // [12]
    float* __restrict__ y)                  // [B][12]
{
    constexpr int RPT = NN / 16;
    __shared__ float tbT[NN][20];
    __shared__ float hb[16][65];

    const int tid = threadIdx.x;
    const int row0 = blockIdx.x * 16;

#pragma unroll
    for (int i = 0; i < NN / 16; ++i) {
        int idx = tid + i * 256;
        int r = idx >> NNSH;
        int c = idx & (NN - 1);
        tbT[c][r] = __bfloat162float(t[(size_t)(row0 + r) * NN + c]);
    }
    __syncthreads();

    const int c = tid & (NN - 1);
    const int rb = (tid >> NNSH) * RPT;
    float acc[RPT];
#pragma unroll
    for (int r = 0; r < RPT; ++r) acc[r] = 0.f;

    for (int mm = 0; mm < NN; ++mm) {
        float lv = Lm[mm * NN + c];
#pragma unroll
        for (int rr = 0; rr < RPT / 4; ++rr) {
            float4 tv = *(const float4*)&tbT[mm][rb + 4 * rr];
            acc[4 * rr + 0] += tv.x * lv;
            acc[4 * rr + 1] += tv.y * lv;
            acc[4 * rr + 2] += tv.z * lv;
            acc[4 * rr + 3] += tv.w * lv;
        }
    }
    float av = a[c];
#pragma unroll
    for (int r = 0; r < RPT; ++r) {
        float hv = (tbT[c][rb + r] + 0.1f * acc[r]) * av;
        if constexpr (FINAL) {
            hb[rb + r][c] = hv;
        } else {
            h[(size_t)(row0 + rb + r) * NN + c] = __float2bfloat16(hv);
        }
    }
    if constexpr (FINAL) {
        __syncthreads();
        if (tid < 192) {
            int r = tid / 12, o = tid - 12 * r;
            float accy = bout[o];
#pragma unroll
            for (int k = 0; k < 64; ++k)
                accy += hb[r][k] * Wout[k * 12 + o];
            y[(size_t)(row0 + r) * 12 + o] = accy;
        }
    }
}

// ---------- fp32 fallback path (round-2 verified) ----------

__global__ __launch_bounds__(256) void liquid_proj_f32(
    const float* __restrict__ x, const float* __restrict__ Wi,
    const float* __restrict__ bi, const float* __restrict__ bl,
    const float* __restrict__ Wo, const float* __restrict__ bo,
    float* __restrict__ t, int K, int Nn)
{
    __shared__ float xs[16][65];
    __shared__ float ws[16][65];
    const int tid = threadIdx.x;
    const int tx = tid & 15, ty = tid >> 4;
    const int row0 = blockIdx.x * 64;
    const int n = blockIdx.y;
    const float* Wn = Wi + (size_t)n * K * 64;
    float acc[4][4] = {};
    for (int k0 = 0; k0 < K; k0 += 16) {
#pragma unroll
        for (int i = 0; i < 4; ++i) {
            int li = tid + 256 * i;
            xs[li & 15][li >> 4] = x[(size_t)(row0 + (li >> 4)) * K + k0 + (li & 15)];
        }
#pragma unroll
        for (int i = 0; i < 4; ++i) {
            int li = tid + 256 * i;
            ws[li >> 6][li & 63] = Wn[(size_t)(k0 + (li >> 6)) * 64 + (li & 63)];
        }
        __syncthreads();
#pragma unroll
        for (int kk = 0; kk < 16; ++kk) {
            float xa[4], wb[4];
#pragma unroll
            for (int i = 0; i < 4; ++i) xa[i] = xs[kk][4 * ty + i];
#pragma unroll
            for (int j = 0; j < 4; ++j) wb[j] = ws[kk][4 * tx + j];
#pragma unroll
            for (int i = 0; i < 4; ++i)
#pragma unroll
                for (int j = 0; j < 4; ++j) acc[i][j] += xa[i] * wb[j];
        }
        __syncthreads();
    }
    float part[4] = {0.f, 0.f, 0.f, 0.f};
#pragma unroll
    for (int j = 0; j < 4; ++j) {
        int cc = 4 * tx + j;
        float bias = bi[n * 64 + cc] + bl[n * 64 + cc];
        float wov = Wo[n * 64 + cc];
#pragma unroll
        for (int i = 0; i < 4; ++i) {
            float v = acc[i][j] + bias;
            part[i] += (tanhf(v) + 0.1f * sinf(0.5f * v) * cosf(0.3f * v)) * wov;
        }
    }
#pragma unroll
    for (int mk = 1; mk < 16; mk <<= 1)
#pragma unroll
        for (int i = 0; i < 4; ++i) part[i] += __shfl_xor(part[i], mk, 64);
    if (tx == 0) {
        float b = bo[n];
#pragma unroll
        for (int i = 0; i < 4; ++i)
            t[(size_t)(row0 + 4 * ty + i) * Nn + n] = part[i] + b;
    }
}

__global__ void lateral_f32_kernel(const float* __restrict__ t,
                                   const float* __restrict__ L,
                                   const float* __restrict__ a,
                                   float* __restrict__ h, int Nn)
{
    extern __shared__ float tb[];
    const int b = blockIdx.x;
    const int n = threadIdx.x;
    tb[n] = t[(size_t)b * Nn + n];
    __syncthreads();
    float acc = 0.f;
    for (int mm = 0; mm < Nn; ++mm)
        acc += tb[mm] * L[(size_t)mm * Nn + n];
    h[(size_t)b * Nn + n] = (tb[n] + 0.1f * acc) * a[n];
}

__global__ void out_f32_kernel(const float* __restrict__ h,
                               const float* __restrict__ Wout,
                               const float* __restrict__ bout,
                               float* __restrict__ y)
{
    int g = blockIdx.x * blockDim.x + threadIdx.x;
    if (g >= BATCH * 12) return;
    int b = g / 12, o = g - 12 * b;
    float acc = bout[o];
    const float* hb = h + (size_t)b * 64;
#pragma unroll
    for (int k = 0; k < 64; ++k) acc += hb[k] * Wout[k * 12 + o];
    y[g] = acc;
}

extern "C" void kernel_launch(void* const* d_in, const int* in_sizes, int n_in,
                              void* d_out, int out_size, void* d_ws, size_t ws_size,
                              hipStream_t stream)
{
    (void)in_sizes; (void)n_in; (void)out_size;
    const float* x = (const float*)d_in[0];
    const float* Wout = (const float*)d_in[22];
    const float* bout = (const float*)d_in[23];
    const int dims[4] = {512, 256, 128, 64};
    char* ws = (char*)d_ws;
    const size_t MB = 1024u * 1024u;

    if (ws_size >= 28 * MB) {
        // Wt0 [0,16) Wt1 [16,20) Wt2 [20,21) xb [21,25) (h0 [21,23), h1 [23,24))
        // tbuf [25,27)  table [27, 27+4.2KB)
        __hip_bfloat16* Wt0 = (__hip_bfloat16*)ws;
        __hip_bfloat16* Wt1 = (__hip_bfloat16*)(ws + 16 * MB);
        __hip_bfloat16* Wt2 = (__hip_bfloat16*)(ws + 20 * MB);
        __hip_bfloat16* Wts[3] = {Wt0, Wt1, Wt2};
        __hip_bfloat16* xb = (__hip_bfloat16*)(ws + 21 * MB);
        __hip_bfloat16* h0 = xb;
        __hip_bfloat16* h1 = (__hip_bfloat16*)(ws + 23 * MB);
        __hip_bfloat16* tbuf = (__hip_bfloat16*)(ws + 25 * MB);
        float* Tg = (float*)(ws + 27 * MB);

        conv_all<<<4737, 256, 0, stream>>>(
            x, xb, (const float*)d_in[1], (const float*)d_in[8],
            (const float*)d_in[15], Wt0, Wt1, Wt2, Tg);

        const __hip_bfloat16* prev = xb;
        const __hip_bfloat16* hbuf[3] = {h0, h1, nullptr};
        for (int l = 0; l < 3; ++l) {
            const float* bi = (const float*)d_in[1 + 7 * l + 1];
            const float* bl = (const float*)d_in[1 + 7 * l + 2];
            const float* Wo = (const float*)d_in[1 + 7 * l + 3];
            const float* bo = (const float*)d_in[1 + 7 * l + 4];
            const float* L  = (const float*)d_in[1 + 7 * l + 5];
            const float* a  = (const float*)d_in[1 + 7 * l + 6];
            const int K = dims[l], Nn = dims[l + 1];

            liquid_proj_mfma<<<32 * (Nn / 4), 512, 0, stream>>>(
                prev, Wts[l], bi, bl, Wo, bo, Tg, tbuf, K, Nn);
            if (l == 0)
                lateral_fused<256, 8, false><<<BATCH / 16, 256, 0, stream>>>(
                    tbuf, L, a, h0, nullptr, nullptr, nullptr);
            else if (l == 1)
                lateral_fused<128, 7, false><<<BATCH / 16, 256, 0, stream>>>(
                    tbuf, L, a, h1, nullptr, nullptr, nullptr);
            else
                lateral_fused<64, 6, true><<<BATCH / 16, 256, 0, stream>>>(
                    tbuf, L, a, nullptr, Wout, bout, (float*)d_out);
            prev = hbuf[l];
        }
    } else {
        float* tbufs[3] = {(float*)ws, (float*)ws, (float*)(ws + 4 * MB)};
        float* hs[3] = {(float*)(ws + 4 * MB), (float*)(ws + 2 * MB),
                        (float*)(ws + 5 * MB)};
        const float* prev = x;
        for (int l = 0; l < 3; ++l) {
            const float* Wi = (const float*)d_in[1 + 7 * l + 0];
            const float* bi = (const float*)d_in[1 + 7 * l + 1];
            const float* bl = (const float*)d_in[1 + 7 * l + 2];
            const float* Wo = (const float*)d_in[1 + 7 * l + 3];
            const float* bo = (const float*)d_in[1 + 7 * l + 4];
            const float* L  = (const float*)d_in[1 + 7 * l + 5];
            const float* a  = (const float*)d_in[1 + 7 * l + 6];
            const int K = dims[l], Nn = dims[l + 1];
            liquid_proj_f32<<<dim3(BATCH / 64, Nn), 256, 0, stream>>>(
                prev, Wi, bi, bl, Wo, bo, tbufs[l], K, Nn);
            lateral_f32_kernel<<<BATCH, Nn, Nn * sizeof(float), stream>>>(
                tbufs[l], L, a, hs[l], Nn);
            prev = hs[l];
        }
        out_f32_kernel<<<(BATCH * 12 + 255) / 256, 256, 0, stream>>>(
            hs[2], Wout, bout, (float*)d_out);
    }
}

// Round 13
// 277.510 us; speedup vs baseline: 1.1461x; 1.0284x over previous
//
#include <hip/hip_runtime.h>
#include <hip/hip_bf16.h>
#include <math.h>

// LiquidNeuralNetwork: B=4096, IN=512, HS={256,128,64}, S=64, OUT=12
// Round 13: r11 proj structure (512 threads, 8 waves, known tripwire-clean)
// + float2-pair LUT only (one ds_read_b64 per activation, 512 intervals).
// r12's 128-thread restructure reverted (post-timing divergence).

#define BATCH 4096

typedef __bf16 bf16x8 __attribute__((ext_vector_type(8)));
typedef float floatx4 __attribute__((ext_vector_type(4)));

__device__ __forceinline__ void gl_lds16(const void* g, void* l) {
    __builtin_amdgcn_global_load_lds(
        (const __attribute__((address_space(1))) void*)g,
        (__attribute__((address_space(3))) void*)l, 16, 0, 0);
}

__device__ __forceinline__ float act_exact(float v) {
    return tanhf(v) + 0.1f * sinf(0.5f * v) * cosf(0.3f * v);
}

// ---------- merged conversion pre-pass + table build ----------

__device__ __forceinline__ void wconv_tile(const float* __restrict__ Wi,
                                           __hip_bfloat16* __restrict__ Wt,
                                           int K, int n, int k0, int t)
{
    __shared__ float lds[64][65];
    const float* src = Wi + ((size_t)n * K + k0) * 64;
#pragma unroll
    for (int i = 0; i < 4; ++i) {
        int idx = t + i * 256;
        int r = idx >> 4;
        int s4 = (idx & 15) * 4;
        float4 v = *(const float4*)(src + (size_t)r * 64 + s4);
        lds[s4 + 0][r] = v.x;
        lds[s4 + 1][r] = v.y;
        lds[s4 + 2][r] = v.z;
        lds[s4 + 3][r] = v.w;
    }
    __syncthreads();
    __hip_bfloat16* dst = Wt + (size_t)n * 64 * K + k0;
#pragma unroll
    for (int i = 0; i < 4; ++i) {
        int idx = t + i * 256;
        int s = idx >> 4;
        int k4 = (idx & 15) * 4;
        union { ushort4 u4; __hip_bfloat16 b[4]; } o;
        o.b[0] = __float2bfloat16(lds[s][k4 + 0]);
        o.b[1] = __float2bfloat16(lds[s][k4 + 1]);
        o.b[2] = __float2bfloat16(lds[s][k4 + 2]);
        o.b[3] = __float2bfloat16(lds[s][k4 + 3]);
        *(ushort4*)(dst + (size_t)s * K + k4) = o.u4;
    }
}

// [0,2048): xconv; [2048,4096): Wi0; [4096,4608): Wi1; [4608,4736): Wi2;
// 4736: activation table: 512 float2 pairs (f(i), f(i+1)), v=(i-256)/32.
__global__ __launch_bounds__(256) void conv_all(
    const float* __restrict__ x, __hip_bfloat16* __restrict__ xb,
    const float* __restrict__ Wi0, const float* __restrict__ Wi1,
    const float* __restrict__ Wi2,
    __hip_bfloat16* __restrict__ Wt0, __hip_bfloat16* __restrict__ Wt1,
    __hip_bfloat16* __restrict__ Wt2, float* __restrict__ Tg)
{
    int bid = blockIdx.x;
    int t = threadIdx.x;
    if (bid < 2048) {
        int g = bid * 256 + t;
        float4 v = ((const float4*)x)[g];
        union { ushort4 u4; __hip_bfloat16 b[4]; } o;
        o.b[0] = __float2bfloat16(v.x);
        o.b[1] = __float2bfloat16(v.y);
        o.b[2] = __float2bfloat16(v.z);
        o.b[3] = __float2bfloat16(v.w);
        ((ushort4*)xb)[g] = o.u4;
    } else if (bid < 4096) {
        int r = bid - 2048;
        wconv_tile(Wi0, Wt0, 512, r >> 3, (r & 7) * 64, t);
    } else if (bid < 4608) {
        int r = bid - 4096;
        wconv_tile(Wi1, Wt1, 256, r >> 2, (r & 3) * 64, t);
    } else if (bid < 4736) {
        int r = bid - 4608;
        wconv_tile(Wi2, Wt2, 128, r >> 1, (r & 1) * 64, t);
    } else {
#pragma unroll
        for (int i = 0; i < 2; ++i) {
            int e = t + 256 * i;          // [0,512)
            float v0 = (float)(e - 256) * 0.03125f;
            Tg[2 * e] = act_exact(v0);
            Tg[2 * e + 1] = act_exact(v0 + 0.03125f);
        }
    }
}

// ---------- MFMA proj: t[b,n] = sum_s act(x@Wi + bi + bl)*Wo + bo ----------
// Block: 512 threads = 8 waves (2 batch-halves x 4 neurons); 128 batch x 4 n.
// Per-wave tile 64s x 64b: acc[4][4]. TRANSPOSED (A=Wt, B=X):
// D[s = rt*16+qd*4+reg][b = wb*64+ct*16+m]. In-register Wo-dot, 2-shfl reduce.

__global__ __launch_bounds__(512, 4) void liquid_proj_mfma(
    const __hip_bfloat16* __restrict__ X,   // [B][K] bf16
    const __hip_bfloat16* __restrict__ Wt,  // [Nn][64][K] bf16
    const float* __restrict__ bi, const float* __restrict__ bl,
    const float* __restrict__ Wo, const float* __restrict__ bo,
    const float* __restrict__ Tg,           // [1024] float2-pair table
    __hip_bfloat16* __restrict__ t, int K, int Nn)
{
    __shared__ __align__(16) __hip_bfloat16 As[128 * 64];   // 16 KB (X tile)
    __shared__ __align__(16) __hip_bfloat16 Bs[256 * 64];   // 32 KB (Wt tile)
    __shared__ __align__(16) float Tt[1024];                // 4 KB

    const int tid = threadIdx.x;
    const int wid = tid >> 6;
    const int wb = wid & 1;               // batch half (64 rows each)
    const int wn = wid >> 1;              // neuron within block [0,4)
    const int lane = tid & 63;
    const int m = lane & 15;
    const int qd = lane >> 4;

    // swizzle: bid = (n_grp*4 + row_local)*8 + xcd ; row_grp = row_local*8+xcd
    const int bid = blockIdx.x;
    const int xcd = bid & 7;
    const int sw = bid >> 3;
    const int n_grp = sw >> 2;
    const int row_grp = ((sw & 3) << 3) | xcd;   // [0,32)
    const int row0 = row_grp * 128;
    const int n0 = n_grp * 4;
    const int n = n0 + wn;

    // table -> LDS: 256 16B chunks (waves 0..3, one chunk each)
    if (tid < 256)
        gl_lds16(Tg + tid * 4, (void*)(Tt + tid * 4));

    // bias folded into acc init; s = rt*16 + qd*4 + reg (same for all ct)
    floatx4 acc[4][4];
#pragma unroll
    for (int rt = 0; rt < 4; ++rt) {
        int sb = n * 64 + rt * 16 + qd * 4;
        float4 b4i = *(const float4*)(bi + sb);
        float4 b4l = *(const float4*)(bl + sb);
        floatx4 b4 = {b4i.x + b4l.x, b4i.y + b4l.y, b4i.z + b4l.z, b4i.w + b4l.w};
#pragma unroll
        for (int ct = 0; ct < 4; ++ct)
            acc[rt][ct] = b4;
    }

    // A(X) staging: 1024 chunks, 2/thread; slot c, source chunk (r, q^(r&7))
    const int ar0 = tid >> 3;
    const int aq0 = (tid & 7) ^ (ar0 & 7);
    const int ar1 = (tid + 512) >> 3;
    const int aq1 = ((tid + 512) & 7) ^ (ar1 & 7);
    const __hip_bfloat16* Xr0 = X + (size_t)(row0 + ar0) * K + aq0 * 8;
    const __hip_bfloat16* Xr1 = X + (size_t)(row0 + ar1) * K + aq1 * 8;

    // B(Wt) staging: 2048 chunks, 4/thread
    const __hip_bfloat16* bsrc[4];
#pragma unroll
    for (int i = 0; i < 4; ++i) {
        int Li = i * 512 + tid;
        int c = Li >> 3;                 // s-row [0,256)
        int q = (Li & 7) ^ (c & 7);
        bsrc[i] = Wt + ((size_t)(n0 + (c >> 6)) * 64 + (c & 63)) * K + q * 8;
    }

    for (int k0 = 0; k0 < K; k0 += 64) {
        gl_lds16(Xr0 + k0, (void*)(As + tid * 8));
        gl_lds16(Xr1 + k0, (void*)(As + ((size_t)tid + 512) * 8));
#pragma unroll
        for (int i = 0; i < 4; ++i)
            gl_lds16(bsrc[i] + k0, (void*)(Bs + ((size_t)i * 512 + tid) * 8));
        __syncthreads();
#pragma unroll
        for (int kk = 0; kk < 2; ++kk) {
            bf16x8 af[4], bfr[4];
#pragma unroll
            for (int rt = 0; rt < 4; ++rt) {          // A = Wt s-rows
                int sr = wn * 64 + rt * 16 + m;
                int slot = sr * 8 + ((kk * 4 + qd) ^ (sr & 7));
                af[rt] = *(const bf16x8*)(Bs + slot * 8);
            }
#pragma unroll
            for (int ct = 0; ct < 4; ++ct) {          // B = X batch-rows
                int br = wb * 64 + ct * 16 + m;
                int slot = br * 8 + ((kk * 4 + qd) ^ (br & 7));
                bfr[ct] = *(const bf16x8*)(As + slot * 8);
            }
#pragma unroll
            for (int rt = 0; rt < 4; ++rt)
#pragma unroll
                for (int ct = 0; ct < 4; ++ct)
                    acc[rt][ct] = __builtin_amdgcn_mfma_f32_16x16x32_bf16(
                        af[rt], bfr[ct], acc[rt][ct], 0, 0, 0);
        }
        __syncthreads();
    }

    // Epilogue: s = rt*16+qd*4+reg, b = wb*64+ct*16+m. In-register Wo-dot.
    float wo[4][4];
#pragma unroll
    for (int rt = 0; rt < 4; ++rt) {
        float4 w4 = *(const float4*)(Wo + n * 64 + rt * 16 + qd * 4);
        wo[rt][0] = w4.x; wo[rt][1] = w4.y; wo[rt][2] = w4.z; wo[rt][3] = w4.w;
    }
    float bov = bo[n];
    float p[4] = {0.f, 0.f, 0.f, 0.f};
    const float2* Tt2 = (const float2*)Tt;
#pragma unroll
    for (int ct = 0; ct < 4; ++ct)
#pragma unroll
        for (int rt = 0; rt < 4; ++rt)
#pragma unroll
            for (int reg = 0; reg < 4; ++reg) {
                float v = acc[rt][ct][reg];
                float u = fmaf(v, 32.f, 256.f);
                u = fminf(fmaxf(u, 0.f), 510.99f);
                float fi = floorf(u);
                int ii = (int)fi;
                float fr = u - fi;
                float2 pr = Tt2[ii];
                p[ct] = fmaf(fmaf(fr, pr.y - pr.x, pr.x), wo[rt][reg], p[ct]);
            }
#pragma unroll
    for (int ct = 0; ct < 4; ++ct) {
        p[ct] += __shfl_xor(p[ct], 16, 64);
        p[ct] += __shfl_xor(p[ct], 32, 64);
    }
    if (qd == 0) {
#pragma unroll
        for (int ct = 0; ct < 4; ++ct)
            t[(size_t)(row0 + wb * 64 + ct * 16 + m) * Nn + n] =
                __float2bfloat16(p[ct] + bov);
    }
}

// ---------- lateral (+ fused output head on final layer) ----------

template <int NN, int NNSH, bool FINAL>
__global__ __launch_bounds__(256) void lateral_fused(
    const __hip_bfloat16* __restrict__ t,   // [B][NN] bf16
    const float* __restrict__ Lm,           // [NN][NN]
    const float* __restrict__ a,            // [NN]
    __hip_bfloat16* __restrict__ h,         // [B][NN] bf16 (unused if FINAL)
    const float* __restrict__ Wout,         // [64][12] (FINAL only)
    const float* __restrict__ bout,         // [12]
    float* __restrict__ y)                  // [B][12]
{
    constexpr int RPT = NN / 16;
    __shared__ float tbT[NN][20];
    __shared__ float hb[16][65];

    const int tid = threadIdx.x;
    const int row0 = blockIdx.x * 16;

#pragma unroll
    for (int i = 0; i < NN / 16; ++i) {
        int idx = tid + i * 256;
        int r = idx >> NNSH;
        int c = idx & (NN - 1);
        tbT[c][r] = __bfloat162float(t[(size_t)(row0 + r) * NN + c]);
    }
    __syncthreads();

    const int c = tid & (NN - 1);
    const int rb = (tid >> NNSH) * RPT;
    float acc[RPT];
#pragma unroll
    for (int r = 0; r < RPT; ++r) acc[r] = 0.f;

    for (int mm = 0; mm < NN; ++mm) {
        float lv = Lm[mm * NN + c];
#pragma unroll
        for (int rr = 0; rr < RPT / 4; ++rr) {
            float4 tv = *(const float4*)&tbT[mm][rb + 4 * rr];
            acc[4 * rr + 0] += tv.x * lv;
            acc[4 * rr + 1] += tv.y * lv;
            acc[4 * rr + 2] += tv.z * lv;
            acc[4 * rr + 3] += tv.w * lv;
        }
    }
    float av = a[c];
#pragma unroll
    for (int r = 0; r < RPT; ++r) {
        float hv = (tbT[c][rb + r] + 0.1f * acc[r]) * av;
        if constexpr (FINAL) {
            hb[rb + r][c] = hv;
        } else {
            h[(size_t)(row0 + rb + r) * NN + c] = __float2bfloat16(hv);
        }
    }
    if constexpr (FINAL) {
        __syncthreads();
        if (tid < 192) {
            int r = tid / 12, o = tid - 12 * r;
            float accy = bout[o];
#pragma unroll
            for (int k = 0; k < 64; ++k)
                accy += hb[r][k] * Wout[k * 12 + o];
            y[(size_t)(row0 + r) * 12 + o] = accy;
        }
    }
}

// ---------- fp32 fallback path (round-2 verified) ----------

__global__ __launch_bounds__(256) void liquid_proj_f32(
    const float* __restrict__ x, const float* __restrict__ Wi,
    const float* __restrict__ bi, const float* __restrict__ bl,
    const float* __restrict__ Wo, const float* __restrict__ bo,
    float* __restrict__ t, int K, int Nn)
{
    __shared__ float xs[16][65];
    __shared__ float ws[16][65];
    const int tid = threadIdx.x;
    const int tx = tid & 15, ty = tid >> 4;
    const int row0 = blockIdx.x * 64;
    const int n = blockIdx.y;
    const float* Wn = Wi + (size_t)n * K * 64;
    float acc[4][4] = {};
    for (int k0 = 0; k0 < K; k0 += 16) {
#pragma unroll
        for (int i = 0; i < 4; ++i) {
            int li = tid + 256 * i;
            xs[li & 15][li >> 4] = x[(size_t)(row0 + (li >> 4)) * K + k0 + (li & 15)];
        }
#pragma unroll
        for (int i = 0; i < 4; ++i) {
            int li = tid + 256 * i;
            ws[li >> 6][li & 63] = Wn[(size_t)(k0 + (li >> 6)) * 64 + (li & 63)];
        }
        __syncthreads();
#pragma unroll
        for (int kk = 0; kk < 16; ++kk) {
            float xa[4], wb[4];
#pragma unroll
            for (int i = 0; i < 4; ++i) xa[i] = xs[kk][4 * ty + i];
#pragma unroll
            for (int j = 0; j < 4; ++j) wb[j] = ws[kk][4 * tx + j];
#pragma unroll
            for (int i = 0; i < 4; ++i)
#pragma unroll
                for (int j = 0; j < 4; ++j) acc[i][j] += xa[i] * wb[j];
        }
        __syncthreads();
    }
    float part[4] = {0.f, 0.f, 0.f, 0.f};
#pragma unroll
    for (int j = 0; j < 4; ++j) {
        int cc = 4 * tx + j;
        float bias = bi[n * 64 + cc] + bl[n * 64 + cc];
        float wov = Wo[n * 64 + cc];
#pragma unroll
        for (int i = 0; i < 4; ++i) {
            float v = acc[i][j] + bias;
            part[i] += (tanhf(v) + 0.1f * sinf(0.5f * v) * cosf(0.3f * v)) * wov;
        }
    }
#pragma unroll
    for (int mk = 1; mk < 16; mk <<= 1)
#pragma unroll
        for (int i = 0; i < 4; ++i) part[i] += __shfl_xor(part[i], mk, 64);
    if (tx == 0) {
        float b = bo[n];
#pragma unroll
        for (int i = 0; i < 4; ++i)
            t[(size_t)(row0 + 4 * ty + i) * Nn + n] = part[i] + b;
    }
}

__global__ void lateral_f32_kernel(const float* __restrict__ t,
                                   const float* __restrict__ L,
                                   const float* __restrict__ a,
                                   float* __restrict__ h, int Nn)
{
    extern __shared__ float tb[];
    const int b = blockIdx.x;
    const int n = threadIdx.x;
    tb[n] = t[(size_t)b * Nn + n];
    __syncthreads();
    float acc = 0.f;
    for (int mm = 0; mm < Nn; ++mm)
        acc += tb[mm] * L[(size_t)mm * Nn + n];
    h[(size_t)b * Nn + n] = (tb[n] + 0.1f * acc) * a[n];
}

__global__ void out_f32_kernel(const float* __restrict__ h,
                               const float* __restrict__ Wout,
                               const float* __restrict__ bout,
                               float* __restrict__ y)
{
    int g = blockIdx.x * blockDim.x + threadIdx.x;
    if (g >= BATCH * 12) return;
    int b = g / 12, o = g - 12 * b;
    float acc = bout[o];
    const float* hb = h + (size_t)b * 64;
#pragma unroll
    for (int k = 0; k < 64; ++k) acc += hb[k] * Wout[k * 12 + o];
    y[g] = acc;
}

extern "C" void kernel_launch(void* const* d_in, const int* in_sizes, int n_in,
                              void* d_out, int out_size, void* d_ws, size_t ws_size,
                              hipStream_t stream)
{
    (void)in_sizes; (void)n_in; (void)out_size;
    const float* x = (const float*)d_in[0];
    const float* Wout = (const float*)d_in[22];
    const float* bout = (const float*)d_in[23];
    const int dims[4] = {512, 256, 128, 64};
    char* ws = (char*)d_ws;
    const size_t MB = 1024u * 1024u;

    if (ws_size >= 28 * MB) {
        // Wt0 [0,16) Wt1 [16,20) Wt2 [20,21) xb [21,25) (h0 [21,23), h1 [23,24))
        // tbuf [25,27)  table [27, 27+4KB)
        __hip_bfloat16* Wt0 = (__hip_bfloat16*)ws;
        __hip_bfloat16* Wt1 = (__hip_bfloat16*)(ws + 16 * MB);
        __hip_bfloat16* Wt2 = (__hip_bfloat16*)(ws + 20 * MB);
        __hip_bfloat16* Wts[3] = {Wt0, Wt1, Wt2};
        __hip_bfloat16* xb = (__hip_bfloat16*)(ws + 21 * MB);
        __hip_bfloat16* h0 = xb;
        __hip_bfloat16* h1 = (__hip_bfloat16*)(ws + 23 * MB);
        __hip_bfloat16* tbuf = (__hip_bfloat16*)(ws + 25 * MB);
        float* Tg = (float*)(ws + 27 * MB);

        conv_all<<<4737, 256, 0, stream>>>(
            x, xb, (const float*)d_in[1], (const float*)d_in[8],
            (const float*)d_in[15], Wt0, Wt1, Wt2, Tg);

        const __hip_bfloat16* prev = xb;
        const __hip_bfloat16* hbuf[3] = {h0, h1, nullptr};
        for (int l = 0; l < 3; ++l) {
            const float* bi = (const float*)d_in[1 + 7 * l + 1];
            const float* bl = (const float*)d_in[1 + 7 * l + 2];
            const float* Wo = (const float*)d_in[1 + 7 * l + 3];
            const float* bo = (const float*)d_in[1 + 7 * l + 4];
            const float* L  = (const float*)d_in[1 + 7 * l + 5];
            const float* a  = (const float*)d_in[1 + 7 * l + 6];
            const int K = dims[l], Nn = dims[l + 1];

            liquid_proj_mfma<<<32 * (Nn / 4), 512, 0, stream>>>(
                prev, Wts[l], bi, bl, Wo, bo, Tg, tbuf, K, Nn);
            if (l == 0)
                lateral_fused<256, 8, false><<<BATCH / 16, 256, 0, stream>>>(
                    tbuf, L, a, h0, nullptr, nullptr, nullptr);
            else if (l == 1)
                lateral_fused<128, 7, false><<<BATCH / 16, 256, 0, stream>>>(
                    tbuf, L, a, h1, nullptr, nullptr, nullptr);
            else
                lateral_fused<64, 6, true><<<BATCH / 16, 256, 0, stream>>>(
                    tbuf, L, a, nullptr, Wout, bout, (float*)d_out);
            prev = hbuf[l];
        }
    } else {
        float* tbufs[3] = {(float*)ws, (float*)ws, (float*)(ws + 4 * MB)};
        float* hs[3] = {(float*)(ws + 4 * MB), (float*)(ws + 2 * MB),
                        (float*)(ws + 5 * MB)};
        const float* prev = x;
        for (int l = 0; l < 3; ++l) {
            const float* Wi = (const float*)d_in[1 + 7 * l + 0];
            const float* bi = (const float*)d_in[1 + 7 * l + 1];
            const float* bl = (const float*)d_in[1 + 7 * l + 2];
            const float* Wo = (const float*)d_in[1 + 7 * l + 3];
            const float* bo = (const float*)d_in[1 + 7 * l + 4];
            const float* L  = (const float*)d_in[1 + 7 * l + 5];
            const float* a  = (const float*)d_in[1 + 7 * l + 6];
            const int K = dims[l], Nn = dims[l + 1];
            liquid_proj_f32<<<dim3(BATCH / 64, Nn), 256, 0, stream>>>(
                prev, Wi, bi, bl, Wo, bo, tbufs[l], K, Nn);
            lateral_f32_kernel<<<BATCH, Nn, Nn * sizeof(float), stream>>>(
                tbufs[l], L, a, hs[l], Nn);
            prev = hs[l];
        }
        out_f32_kernel<<<(BATCH * 12 + 255) / 256, 256, 0, stream>>>(
            hs[2], Wout, bout, (float*)d_out);
    }
}